// Round 7
// baseline (61.636 us; speedup 1.0000x reference)
//
#include <hip/hip_runtime.h>

// ROIAlign3D: features [B=2,C=128,D=16,H=64,W=64] f32, rois [B,N=64,6] f32
// out [B,N,C,7,7,7] f32. SAMPLING_RATIO=2, ALIGNED=true, SPATIAL_SCALE=1.
//
// Round 7: fully separable evaluation. Per block (b,n,channel-pair):
//   stage sub (fp16x2)  ->  XP[row][k]   (x-interp once per row/out-k)
//                        ->  YX[z][j][k]  (y-collapse, 4 XP reads)
//                        ->  cell         (4 YX reads + 4 fma)
// LDS reads/block: 21.9K -> ~10.3K; X-build waves have uniform k =>
// wave-uniform x-offsets, stride-25 rows (gcd(25,32)=1) => conflict-free.
// YX reuses sub's LDS (dead after X-build). ~32.8KB => 4 blocks/CU.
constexpr int Bc = 2, Nc = 64, Cc = 128, Dc = 16, Hc = 64, Wc = 64;
constexpr int OD = 7, OH = 7, OW = 7;
constexpr int CELLS = OD * OH * OW;          // 343
constexpr int DHW = Dc * Hc * Wc, HW = Hc * Wc;
constexpr int MAXZ = 10, MAXY = 25, MAXX = 25;
constexpr int XS = 25;                        // fixed x stride in LDS
constexpr int ROWS = MAXZ * MAXY;             // 250
constexpr int SUBSZ = ROWS * XS;              // 6250

typedef __fp16 h2 __attribute__((ext_vector_type(2)));

__device__ inline unsigned pk_f16(float a, float b) {
    return __builtin_bit_cast(unsigned, __builtin_amdgcn_cvt_pkrtz(a, b));
}

__device__ inline float fdot2(unsigned a, unsigned b, float c) {
#if __has_builtin(__builtin_amdgcn_fdot2)
    return __builtin_amdgcn_fdot2(__builtin_bit_cast(h2, a),
                                  __builtin_bit_cast(h2, b), c, false);
#else
    h2 ha = __builtin_bit_cast(h2, a);
    h2 hb = __builtin_bit_cast(h2, b);
    return fmaf((float)ha.x, (float)hb.x, fmaf((float)ha.y, (float)hb.y, c));
#endif
}

__global__ __launch_bounds__(384) void roialign3d_v7(
    const float* __restrict__ feat, const float* __restrict__ rois,
    float* __restrict__ out)
{
    __shared__ __align__(16) unsigned sub[SUBSZ + 2];  // 25008B; reused as YX
    __shared__ unsigned xp[ROWS * 7];                  // 7000B packed fp16x2
    __shared__ int2     tzp[14], typ[14];
    __shared__ float2   wzp[14], wyp[14];
    __shared__ int      txo[14];
    __shared__ unsigned wxh[14];
    __shared__ int      rowglob[ROWS];

    const int blk = blockIdx.x;
    const int cp  = blk & 63;
    const int n   = (blk >> 6) & 63;
    const int b   = blk >> 12;
    const int tid = threadIdx.x;

    const float* rp = rois + (size_t)(b * Nc + n) * 6;
    float r1a[3] = {rp[0] - 0.5f, rp[1] - 0.5f, rp[2] - 0.5f};
    float r2a[3] = {rp[3] - 0.5f, rp[4] - 0.5f, rp[5] - 0.5f};
    const int dims[3] = {Dc, Hc, Wc};
    const int maxn[3] = {MAXZ, MAXY, MAXX};

    float bs[3]; int lo[3], ncnt[3];
    #pragma unroll
    for (int a = 0; a < 3; ++a) {
        bs[a] = fmaxf(r2a[a] - r1a[a], 1e-6f) * (1.0f / 7.0f);
        float smin = r1a[a] + 0.25f * bs[a];
        float smax = r1a[a] + 6.75f * bs[a];
        int l = max(0, (int)floorf(smin));
        int h = min(dims[a] - 1, (int)floorf(smax) + 1);
        lo[a] = l;
        ncnt[a] = min(h - l + 1, maxn[a]);    // maxn clamp = memory safety only
    }
    const int zn = ncnt[0], yn = ncnt[1], xn = ncnt[2];
    const int rows = zn * yn;

    // Axis tables. z offsets premult x49 (YX space), y offsets premult x7
    // (XP space), x raw column (+pair trick) with packed f16 weights.
    if (tid < 42) {
        int a = tid / 14, m = tid - a * 14;
        float v = r1a[a] + ((float)m + 0.5f) * 0.5f * bs[a];
        float f = floorf(v);
        float l = v - f;
        int i0 = (int)f;
        int d  = dims[a];
        float w0 = (i0 >= 0 && i0 < d) ? 1.0f - l : 0.0f;
        float w1 = (i0 + 1 < d) ? l : 0.0f;
        if (a == 0) {
            int c0 = min(max(i0 - lo[0], 0), zn - 1);
            int c1 = min(max(i0 + 1 - lo[0], 0), zn - 1);
            tzp[m] = make_int2(c0 * 49, c1 * 49);
            wzp[m] = make_float2(w0, w1);
        } else if (a == 1) {
            int c0 = min(max(i0 - lo[1], 0), yn - 1);
            int c1 = min(max(i0 + 1 - lo[1], 0), yn - 1);
            typ[m] = make_int2(c0 * 7, c1 * 7);
            wyp[m] = make_float2(w0, w1);
        } else {
            int c0 = min(max(i0 - lo[2], -1), xn - 1);
            txo[m] = c0;
            wxh[m] = pk_f16(w0, w1);
        }
    }
    if (tid >= 128 && tid < 128 + ROWS) {
        int r = tid - 128;
        if (r < rows) {
            int z = r / yn;
            int y = r - z * yn;
            rowglob[r] = (lo[0] + z) * HW + (lo[1] + y) * Wc + lo[2];
        }
    }
    if (tid == 64) sub[0] = 0;                       // front pad (x pair at -1)
    if (tid == 65) sub[1 + rows * XS] = 0;           // element after staged data
    __syncthreads();

    // ---- Stage subvolume (fp16x2 packed), 32-lane row slots. ----
    const int c0ch = cp * 2;
    const float* fb = feat + ((size_t)b * Cc + c0ch) * DHW;
    const int nslots = rows * 32;
    for (int p = tid; p < nslots; p += 384) {
        int row = p >> 5;
        int x   = p & 31;
        if (x < XS) {
            int xs = min(x, xn - 1);
            int g  = rowglob[row] + xs;
            sub[1 + row * XS + x] = pk_f16(fb[g], fb[g + DHW]);
        }
    }
    __syncthreads();

    // ---- X phase: XP[row][k] = x-interp of both samples (m=2k,2k+1). ----
    // e -> (k = e>>8, row = e&255): every wave has uniform k (broadcast
    // tables, wave-uniform column offsets) and consecutive rows (stride 25,
    // coprime with 32 banks -> conflict-free).
    for (int e = tid; e < 7 * 256; e += 384) {
        int k   = e >> 8;
        int row = e & 255;
        if (row < rows) {
            const unsigned* Grow = sub + 1 + row * XS;
            int c0 = txo[2 * k], c1 = txo[2 * k + 1];
            unsigned wh0 = wxh[2 * k], wh1 = wxh[2 * k + 1];
            unsigned p0a = Grow[c0], p0b = Grow[c0 + 1];
            unsigned p1a = Grow[c1], p1b = Grow[c1 + 1];
            unsigned c0p0 = __builtin_amdgcn_perm(p0b, p0a, 0x05040100u);
            unsigned c1p0 = __builtin_amdgcn_perm(p0b, p0a, 0x07060302u);
            unsigned c0p1 = __builtin_amdgcn_perm(p1b, p1a, 0x05040100u);
            unsigned c1p1 = __builtin_amdgcn_perm(p1b, p1a, 0x07060302u);
            float r0 = fdot2(c0p1, wh1, fdot2(c0p0, wh0, 0.0f));
            float r1 = fdot2(c1p1, wh1, fdot2(c1p0, wh0, 0.0f));
            xp[row * 7 + k] = pk_f16(r0, r1);
        }
    }
    __syncthreads();

    // ---- Y phase: YX[z*49 + j*7 + k] (float2, reusing sub's storage). ----
    float2* yx = reinterpret_cast<float2*>(sub);
    const int yn7 = yn * 7;
    const int nyx = zn * 49;
    for (int q = tid; q < nyx; q += 384) {
        int z   = q / 49;
        int rem = q - z * 49;
        int j   = rem / 7;
        int k   = rem - j * 7;
        int base = z * yn7 + k;
        int2   t0 = typ[2 * j], t1 = typ[2 * j + 1];
        float2 w0 = wyp[2 * j], w1 = wyp[2 * j + 1];
        h2 pa = __builtin_bit_cast(h2, xp[base + t0.x]);
        h2 pb = __builtin_bit_cast(h2, xp[base + t0.y]);
        h2 pc = __builtin_bit_cast(h2, xp[base + t1.x]);
        h2 pd = __builtin_bit_cast(h2, xp[base + t1.y]);
        float s0 = w0.x * (float)pa.x + w0.y * (float)pb.x
                 + w1.x * (float)pc.x + w1.y * (float)pd.x;
        float s1 = w0.x * (float)pa.y + w0.y * (float)pb.y
                 + w1.x * (float)pc.y + w1.y * (float)pd.y;
        yx[q] = make_float2(s0, s1);
    }
    __syncthreads();

    // ---- Cell phase: 4 YX reads + weighted sum. ----
    if (tid < CELLS) {
        int i   = tid / 49;
        int rem = tid - i * 49;          // = j*7 + k, the YX minor index
        int2   tz0 = tzp[2 * i], tz1 = tzp[2 * i + 1];
        float2 wz0 = wzp[2 * i], wz1 = wzp[2 * i + 1];
        float2 va = yx[tz0.x + rem];
        float2 vb = yx[tz0.y + rem];
        float2 vc = yx[tz1.x + rem];
        float2 vd = yx[tz1.y + rem];
        float a0 = wz0.x * va.x + wz0.y * vb.x + wz1.x * vc.x + wz1.y * vd.x;
        float a1 = wz0.x * va.y + wz0.y * vb.y + wz1.x * vc.y + wz1.y * vd.y;
        size_t obase = ((size_t)(b * Nc + n) * Cc + c0ch) * CELLS;
        out[obase + tid]         = a0 * 0.125f;
        out[obase + CELLS + tid] = a1 * 0.125f;
    }
}

extern "C" void kernel_launch(void* const* d_in, const int* in_sizes, int n_in,
                              void* d_out, int out_size, void* d_ws, size_t ws_size,
                              hipStream_t stream) {
    const float* feat = (const float*)d_in[0];
    const float* rois = (const float*)d_in[1];
    float* out = (float*)d_out;
    int blocks = Bc * Nc * (Cc / 2);   // 8192
    hipLaunchKernelGGL(roialign3d_v7, dim3(blocks), dim3(384), 0, stream,
                       feat, rois, out);
}

// Round 8
// 57.637 us; speedup vs baseline: 1.0694x; 1.0694x over previous
//
#include <hip/hip_runtime.h>

// ROIAlign3D: features [B=2,C=128,D=16,H=64,W=64] f32, rois [B,N=64,6] f32
// out [B,N,C,7,7,7] f32. SAMPLING_RATIO=2, ALIGNED=true, SPATIAL_SCALE=1.
//
// Round 8: v6 fused structure (2 barriers, no phase split — v7 showed phase
// serialization loses), but 4 channels per block packed as uint2 (2x fp16x2)
// per voxel. An x-pair read = two adjacent uint2 loads -> compiler merges to
// ds_read2_b64: 2 LDS read-instrs per (zi,yi) serving 4 channels (v6: 4 b32
// serving 2). Per-CU LDS instruction count (the v6 limiter) drops ~2.6x.
constexpr int Bc = 2, Nc = 64, Cc = 128, Dc = 16, Hc = 64, Wc = 64;
constexpr int OD = 7, OH = 7, OW = 7;
constexpr int CELLS = OD * OH * OW;          // 343
constexpr int DHW = Dc * Hc * Wc, HW = Hc * Wc;
constexpr int MAXZ = 10, MAXY = 25, MAXX = 25;
constexpr int XS = 25;                        // fixed x stride in LDS
constexpr int ROWS = MAXZ * MAXY;             // 250
constexpr int SUBSZ = ROWS * XS;              // 6250 voxels

typedef __fp16 h2 __attribute__((ext_vector_type(2)));

__device__ inline unsigned pk_f16(float a, float b) {
    return __builtin_bit_cast(unsigned, __builtin_amdgcn_cvt_pkrtz(a, b));
}

__device__ inline float fdot2(unsigned a, unsigned b, float c) {
#if __has_builtin(__builtin_amdgcn_fdot2)
    return __builtin_amdgcn_fdot2(__builtin_bit_cast(h2, a),
                                  __builtin_bit_cast(h2, b), c, false);
#else
    h2 ha = __builtin_bit_cast(h2, a);
    h2 hb = __builtin_bit_cast(h2, b);
    return fmaf((float)ha.x, (float)hb.x, fmaf((float)ha.y, (float)hb.y, c));
#endif
}

__global__ __launch_bounds__(384) void roialign3d_v8(
    const float* __restrict__ feat, const float* __restrict__ rois,
    float* __restrict__ out)
{
    __shared__ __align__(16) uint2 sub[SUBSZ + 2];   // 50,016 B; [0] front pad
    __shared__ int2     tzp[14], typ[14];
    __shared__ float2   wzp[14], wyp[14];
    __shared__ int      txo[14];
    __shared__ unsigned wxh[14];              // packed f16 (w_left, w_right)
    __shared__ int      rowglob[ROWS];

    const int blk = blockIdx.x;
    const int cq  = blk & 31;           // channel quad (c = 4cq .. 4cq+3)
    const int n   = (blk >> 5) & 63;
    const int b   = blk >> 11;
    const int tid = threadIdx.x;

    const float* rp = rois + (size_t)(b * Nc + n) * 6;
    float r1a[3] = {rp[0] - 0.5f, rp[1] - 0.5f, rp[2] - 0.5f};
    float r2a[3] = {rp[3] - 0.5f, rp[4] - 0.5f, rp[5] - 0.5f};
    const int dims[3] = {Dc, Hc, Wc};
    const int maxn[3] = {MAXZ, MAXY, MAXX};

    float bs[3]; int lo[3], ncnt[3];
    #pragma unroll
    for (int a = 0; a < 3; ++a) {
        bs[a] = fmaxf(r2a[a] - r1a[a], 1e-6f) * (1.0f / 7.0f);
        float smin = r1a[a] + 0.25f * bs[a];
        float smax = r1a[a] + 6.75f * bs[a];
        int l = max(0, (int)floorf(smin));
        int h = min(dims[a] - 1, (int)floorf(smax) + 1);
        lo[a] = l;
        ncnt[a] = min(h - l + 1, maxn[a]);    // maxn clamp = memory safety only
    }
    const int zn = ncnt[0], yn = ncnt[1], xn = ncnt[2];
    const int rows = zn * yn;
    const int zstride = yn * XS;

    // Axis tables (42 threads) + per-row global offsets + pads.
    if (tid < 42) {
        int a = tid / 14, m = tid - a * 14;
        float v = r1a[a] + ((float)m + 0.5f) * 0.5f * bs[a];
        float f = floorf(v);
        float l = v - f;
        int i0 = (int)f;
        int d  = dims[a];
        float w0 = (i0 >= 0 && i0 < d) ? 1.0f - l : 0.0f;
        float w1 = (i0 + 1 < d) ? l : 0.0f;
        if (a == 0) {
            int c0 = min(max(i0 - lo[0], 0), zn - 1);
            int c1 = min(max(i0 + 1 - lo[0], 0), zn - 1);
            tzp[m] = make_int2(c0 * zstride, c1 * zstride);
            wzp[m] = make_float2(w0, w1);
        } else if (a == 1) {
            int c0 = min(max(i0 - lo[1], 0), yn - 1);
            int c1 = min(max(i0 + 1 - lo[1], 0), yn - 1);
            typ[m] = make_int2(c0 * XS, c1 * XS);
            wyp[m] = make_float2(w0, w1);
        } else {
            // pair trick: corners are (c0, c0+1); c0 in [-1, xn-1].
            int c0 = min(max(i0 - lo[2], -1), xn - 1);
            txo[m] = c0;
            wxh[m] = pk_f16(w0, w1);
        }
    }
    if (tid >= 128 && tid < 128 + ROWS) {
        int r = tid - 128;
        if (r < rows) {
            int z = r / yn;
            int y = r - z * yn;
            rowglob[r] = (lo[0] + z) * HW + (lo[1] + y) * Wc + lo[2];
        }
    }
    if (tid == 64) sub[0] = make_uint2(0u, 0u);            // front pad
    if (tid == 65) sub[1 + rows * XS] = make_uint2(0u, 0u); // end pad
    __syncthreads();

    // Stage subvolume for 4 channels, 32-lane row slots; x >= xn duplicates
    // column xn-1 (only read with weight 0) so every slot stays finite.
    const int c0ch = cq * 4;
    const float* fb = feat + ((size_t)b * Cc + c0ch) * DHW;
    const int nslots = rows * 32;
    for (int p = tid; p < nslots; p += 384) {
        int row = p >> 5;
        int x   = p & 31;
        if (x < XS) {
            int xs = min(x, xn - 1);
            int g  = rowglob[row] + xs;
            float v0 = fb[g];
            float v1 = fb[g + DHW];
            float v2 = fb[g + 2 * DHW];
            float v3 = fb[g + 3 * DHW];
            sub[1 + row * XS + x] = make_uint2(pk_f16(v0, v1), pk_f16(v2, v3));
        }
    }
    __syncthreads();

    if (tid < CELLS) {
        int i = tid / 49;
        int rem = tid - i * 49;
        int j = rem / 7, k = rem - j * 7;

        const uint2* G = sub + 1;
        int4   tz = *(const int4*)&tzp[2 * i];
        float4 wzv = *(const float4*)&wzp[2 * i];
        int4   ty = *(const int4*)&typ[2 * j];
        float4 wyv = *(const float4*)&wyp[2 * j];
        int    xo0 = txo[2 * k], xo1 = txo[2 * k + 1];
        unsigned wh0 = wxh[2 * k], wh1 = wxh[2 * k + 1];

        const int   zo[4] = {tz.x, tz.y, tz.z, tz.w};
        const float wz[4] = {wzv.x, wzv.y, wzv.z, wzv.w};
        const int   yo[4] = {ty.x, ty.y, ty.z, ty.w};
        const float wy[4] = {wyv.x, wyv.y, wyv.z, wyv.w};

        float a0 = 0.0f, a1 = 0.0f, a2 = 0.0f, a3 = 0.0f;
        #pragma unroll
        for (int zi = 0; zi < 4; ++zi) {
            #pragma unroll
            for (int yi = 0; yi < 4; ++yi) {
                int base = zo[zi] + yo[yi];
                float Wzy = wz[zi] * wy[yi];
                // sample 0 x-pair (adjacent uint2 -> ds_read2_b64)
                uint2 A0 = G[base + xo0], A1 = G[base + xo0 + 1];
                // sample 1 x-pair
                uint2 B0 = G[base + xo1], B1 = G[base + xo1 + 1];
                unsigned c0s0 = __builtin_amdgcn_perm(A1.x, A0.x, 0x05040100u);
                unsigned c1s0 = __builtin_amdgcn_perm(A1.x, A0.x, 0x07060302u);
                unsigned c2s0 = __builtin_amdgcn_perm(A1.y, A0.y, 0x05040100u);
                unsigned c3s0 = __builtin_amdgcn_perm(A1.y, A0.y, 0x07060302u);
                unsigned c0s1 = __builtin_amdgcn_perm(B1.x, B0.x, 0x05040100u);
                unsigned c1s1 = __builtin_amdgcn_perm(B1.x, B0.x, 0x07060302u);
                unsigned c2s1 = __builtin_amdgcn_perm(B1.y, B0.y, 0x05040100u);
                unsigned c3s1 = __builtin_amdgcn_perm(B1.y, B0.y, 0x07060302u);
                float r0 = fdot2(c0s1, wh1, fdot2(c0s0, wh0, 0.0f));
                float r1 = fdot2(c1s1, wh1, fdot2(c1s0, wh0, 0.0f));
                float r2 = fdot2(c2s1, wh1, fdot2(c2s0, wh0, 0.0f));
                float r3 = fdot2(c3s1, wh1, fdot2(c3s0, wh0, 0.0f));
                a0 = fmaf(Wzy, r0, a0);
                a1 = fmaf(Wzy, r1, a1);
                a2 = fmaf(Wzy, r2, a2);
                a3 = fmaf(Wzy, r3, a3);
            }
        }
        size_t obase = ((size_t)(b * Nc + n) * Cc + c0ch) * CELLS;
        out[obase + tid]             = a0 * 0.125f;
        out[obase + CELLS + tid]     = a1 * 0.125f;
        out[obase + 2 * CELLS + tid] = a2 * 0.125f;
        out[obase + 3 * CELLS + tid] = a3 * 0.125f;
    }
}

extern "C" void kernel_launch(void* const* d_in, const int* in_sizes, int n_in,
                              void* d_out, int out_size, void* d_ws, size_t ws_size,
                              hipStream_t stream) {
    const float* feat = (const float*)d_in[0];
    const float* rois = (const float*)d_in[1];
    float* out = (float*)d_out;
    int blocks = Bc * Nc * (Cc / 4);   // 4096
    hipLaunchKernelGGL(roialign3d_v8, dim3(blocks), dim3(384), 0, stream,
                       feat, rois, out);
}

// Round 9
// 48.788 us; speedup vs baseline: 1.2634x; 1.1814x over previous
//
#include <hip/hip_runtime.h>

// ROIAlign3D: features [B=2,C=128,D=16,H=64,W=64] f32, rois [B,N=64,6] f32
// out [B,N,C,7,7,7] f32. SAMPLING_RATIO=2, ALIGNED=true, SPATIAL_SCALE=1.
//
// Round 9: v6 structure (block = b,n,channel-pair; 384 thr; fused, 2 barriers)
// + z-axis 3-slot collapse: the 4 z sample-corners always lie in
//   {c0,c0+1,c0+2}; scatter weights into 3 coeffs -> 12 inner points not 16
//   (LDS reads 32->24/thread, VALU ~15% down).
// + staging uses p/25 const-div (full 64-lane utilization, no 32-slot pad).
// + cell table loads hoisted above barrier 2 (overlap with staging latency).
constexpr int Bc = 2, Nc = 64, Cc = 128, Dc = 16, Hc = 64, Wc = 64;
constexpr int OD = 7, OH = 7, OW = 7;
constexpr int CELLS = OD * OH * OW;          // 343
constexpr int DHW = Dc * Hc * Wc, HW = Hc * Wc;
constexpr int MAXZ = 10, MAXY = 25, MAXX = 25;
constexpr int XS = 25;                        // fixed x stride in LDS
constexpr int ROWS = MAXZ * MAXY;             // 250
constexpr int SUBSZ = ROWS * XS;              // 6250

typedef __fp16 h2 __attribute__((ext_vector_type(2)));

__device__ inline unsigned pk_f16(float a, float b) {
    return __builtin_bit_cast(unsigned, __builtin_amdgcn_cvt_pkrtz(a, b));
}

__device__ inline float fdot2(unsigned a, unsigned b, float c) {
#if __has_builtin(__builtin_amdgcn_fdot2)
    return __builtin_amdgcn_fdot2(__builtin_bit_cast(h2, a),
                                  __builtin_bit_cast(h2, b), c, false);
#else
    h2 ha = __builtin_bit_cast(h2, a);
    h2 hb = __builtin_bit_cast(h2, b);
    return fmaf((float)ha.x, (float)hb.x, fmaf((float)ha.y, (float)hb.y, c));
#endif
}

__global__ __launch_bounds__(384) void roialign3d_v9(
    const float* __restrict__ feat, const float* __restrict__ rois,
    float* __restrict__ out)
{
    __shared__ unsigned sub[SUBSZ + 2];       // [0]=front pad, data, end pad
    __shared__ int2     tzp[14], typ[14];     // tzp: RAW z rows (c0,c1)
    __shared__ float2   wzp[14], wyp[14];
    __shared__ int      txo[14];
    __shared__ unsigned wxh[14];              // packed f16 (w_left, w_right)
    __shared__ int      rowglob[ROWS];

    const int blk = blockIdx.x;
    const int cp  = blk & 63;
    const int n   = (blk >> 6) & 63;
    const int b   = blk >> 12;
    const int tid = threadIdx.x;

    const float* rp = rois + (size_t)(b * Nc + n) * 6;
    float r1a[3] = {rp[0] - 0.5f, rp[1] - 0.5f, rp[2] - 0.5f};
    float r2a[3] = {rp[3] - 0.5f, rp[4] - 0.5f, rp[5] - 0.5f};
    const int dims[3] = {Dc, Hc, Wc};
    const int maxn[3] = {MAXZ, MAXY, MAXX};

    float bs[3]; int lo[3], ncnt[3];
    #pragma unroll
    for (int a = 0; a < 3; ++a) {
        bs[a] = fmaxf(r2a[a] - r1a[a], 1e-6f) * (1.0f / 7.0f);
        float smin = r1a[a] + 0.25f * bs[a];
        float smax = r1a[a] + 6.75f * bs[a];
        int l = max(0, (int)floorf(smin));
        int h = min(dims[a] - 1, (int)floorf(smax) + 1);
        lo[a] = l;
        ncnt[a] = min(h - l + 1, maxn[a]);    // maxn clamp = memory safety only
    }
    const int zn = ncnt[0], yn = ncnt[1], xn = ncnt[2];
    const int rows = zn * yn;
    const int zstride = yn * XS;

    // Axis tables (42 threads) + per-row global offsets + pads.
    if (tid < 42) {
        int a = tid / 14, m = tid - a * 14;
        float v = r1a[a] + ((float)m + 0.5f) * 0.5f * bs[a];
        float f = floorf(v);
        float l = v - f;
        int i0 = (int)f;
        int d  = dims[a];
        float w0 = (i0 >= 0 && i0 < d) ? 1.0f - l : 0.0f;
        float w1 = (i0 + 1 < d) ? l : 0.0f;
        if (a == 0) {
            int c0 = min(max(i0 - lo[0], 0), zn - 1);
            int c1 = min(max(i0 + 1 - lo[0], 0), zn - 1);
            tzp[m] = make_int2(c0, c1);              // RAW rows
            wzp[m] = make_float2(w0, w1);
        } else if (a == 1) {
            int c0 = min(max(i0 - lo[1], 0), yn - 1);
            int c1 = min(max(i0 + 1 - lo[1], 0), yn - 1);
            typ[m] = make_int2(c0 * XS, c1 * XS);
            wyp[m] = make_float2(w0, w1);
        } else {
            // pair trick: corners are (c0, c0+1); c0 in [-1, xn-1].
            int c0 = min(max(i0 - lo[2], -1), xn - 1);
            txo[m] = c0;
            wxh[m] = pk_f16(w0, w1);
        }
    }
    if (tid >= 128 && tid < 128 + ROWS) {
        int r = tid - 128;
        if (r < rows) {
            int z = r / yn;
            int y = r - z * yn;
            rowglob[r] = (lo[0] + z) * HW + (lo[1] + y) * Wc + lo[2];
        }
    }
    if (tid == 64) sub[0] = 0;                       // front pad (x pair at -1)
    if (tid == 65) sub[1 + rows * XS] = 0;           // element after staged data
    __syncthreads();

    // ---- Stage subvolume (fp16x2), full-lane: row = p/25 (const-div). ----
    const int c0ch = cp * 2;
    const float* fb = feat + ((size_t)b * Cc + c0ch) * DHW;
    const int total = rows * XS;
    for (int p = tid; p < total; p += 384) {
        int row = p / XS;
        int x   = p - row * XS;
        int xs  = min(x, xn - 1);
        int g   = rowglob[row] + xs;
        sub[1 + p] = pk_f16(fb[g], fb[g + DHW]);
    }

    // ---- Hoist cell tables (final since barrier 1) above barrier 2. ----
    int i = 0, j = 0, k = 0;
    int4 tzr; float4 wzv; int4 ty; float4 wyv;
    int xo0 = 0, xo1 = 0; unsigned wh0 = 0, wh1 = 0;
    if (tid < CELLS) {
        i = tid / 49;
        int rem = tid - i * 49;
        j = rem / 7;
        k = rem - j * 7;
        tzr = *(const int4*)&tzp[2 * i];     // (c0, c1, c0', c1') raw rows
        wzv = *(const float4*)&wzp[2 * i];
        ty  = *(const int4*)&typ[2 * j];
        wyv = *(const float4*)&wyp[2 * j];
        xo0 = txo[2 * k]; xo1 = txo[2 * k + 1];
        wh0 = wxh[2 * k]; wh1 = wxh[2 * k + 1];
    }
    __syncthreads();

    if (tid < CELLS) {
        const unsigned* G = sub + 1;

        // z 3-slot collapse: corners lie in {c0, c0+1, c0+2}.
        int c0z = tzr.x;
        int p1 = tzr.y - c0z;               // {0,1}
        int p2 = tzr.z - c0z;               // {0,1}
        int p3 = tzr.w - c0z;               // {0,1,2}
        float cz0 = wzv.x + (p1 == 0 ? wzv.y : 0.0f)
                  + (p2 == 0 ? wzv.z : 0.0f) + (p3 == 0 ? wzv.w : 0.0f);
        float cz1 = (p1 == 1 ? wzv.y : 0.0f)
                  + (p2 == 1 ? wzv.z : 0.0f) + (p3 == 1 ? wzv.w : 0.0f);
        float cz2 = (p3 == 2 ? wzv.w : 0.0f);
        // weight-0 slots clamp to a staged (finite) row.
        int zb0 = c0z * zstride;
        int zb1 = min(c0z + 1, zn - 1) * zstride;
        int zb2 = min(c0z + 2, zn - 1) * zstride;

        const int   zbs[3] = {zb0, zb1, zb2};
        const float czs[3] = {cz0, cz1, cz2};
        const int   yo[4] = {ty.x, ty.y, ty.z, ty.w};
        const float wy[4] = {wyv.x, wyv.y, wyv.z, wyv.w};

        float a0 = 0.0f, a1 = 0.0f;
        #pragma unroll
        for (int d = 0; d < 3; ++d) {
            int zb = zbs[d];
            float s0 = 0.0f, s1 = 0.0f;
            #pragma unroll
            for (int yi = 0; yi < 4; ++yi) {
                int base = zb + yo[yi];
                unsigned p0a = G[base + xo0], p0b = G[base + xo0 + 1];
                unsigned p1a = G[base + xo1], p1b = G[base + xo1 + 1];
                unsigned c0p0 = __builtin_amdgcn_perm(p0b, p0a, 0x05040100u);
                unsigned c1p0 = __builtin_amdgcn_perm(p0b, p0a, 0x07060302u);
                unsigned c0p1 = __builtin_amdgcn_perm(p1b, p1a, 0x05040100u);
                unsigned c1p1 = __builtin_amdgcn_perm(p1b, p1a, 0x07060302u);
                float r0 = fdot2(c0p1, wh1, fdot2(c0p0, wh0, 0.0f));
                float r1 = fdot2(c1p1, wh1, fdot2(c1p0, wh0, 0.0f));
                s0 = fmaf(wy[yi], r0, s0);
                s1 = fmaf(wy[yi], r1, s1);
            }
            a0 = fmaf(czs[d], s0, a0);
            a1 = fmaf(czs[d], s1, a1);
        }
        size_t obase = ((size_t)(b * Nc + n) * Cc + c0ch) * CELLS;
        out[obase + tid]         = a0 * 0.125f;
        out[obase + CELLS + tid] = a1 * 0.125f;
    }
}

extern "C" void kernel_launch(void* const* d_in, const int* in_sizes, int n_in,
                              void* d_out, int out_size, void* d_ws, size_t ws_size,
                              hipStream_t stream) {
    const float* feat = (const float*)d_in[0];
    const float* rois = (const float*)d_in[1];
    float* out = (float*)d_out;
    int blocks = Bc * Nc * (Cc / 2);   // 8192
    hipLaunchKernelGGL(roialign3d_v9, dim3(blocks), dim3(384), 0, stream,
                       feat, rois, out);
}